// Round 1
// baseline (1426.673 us; speedup 1.0000x reference)
//
#include <hip/hip_runtime.h>

typedef __bf16 bf16x8 __attribute__((ext_vector_type(8)));
typedef __bf16 bf16x4 __attribute__((ext_vector_type(4)));
typedef float  f32x4  __attribute__((ext_vector_type(4)));

#define NG 5000
#define NU 100000
#define NI 20000
#define H  128
#define EUG 300000
#define EUI 600000
#define EGI 200000

// ---------------- workspace layout (bytes) ----------------
#define B_AGGU  0UL                    // NU*H f32 = 51,200,000
#define B_AGGI  51200000UL             // NI*H f32 = 10,240,000
#define B_AGGG1 61440000UL             // NG*H f32 = 2,560,000
#define B_AGGG2 64000000UL             // NG*H f32
#define B_AGGG3 66560000UL             // NG*H f32
#define B_BC    69120000UL             // 4*128 f32
#define B_PWT   69122048UL             // NI*H bf16 = 5,120,000
#define B_WT    74242048UL             // 9*16384 bf16 = 294,912
#define B_CNT   74536960UL             // 130,000 int
#define B_OFFS  75056960UL             // 130,004 int
#define B_CUR   75576976UL             // 130,000 int
#define B_EIDX  76096976UL             // 1,700,000 int

// cnt/cur sub-offsets (ints): ug:0, gi:NG, uiu:2*NG, uii:2*NG+NU
// offs sub-offsets (ints):    ug:0, gi:NG+1, uiu:2*(NG+1), uii:2*(NG+1)+(NU+1)
// eidx sub-offsets (ints):    ug:0, gi:EUG, uiu:EUG+EGI, uii:EUG+EGI+EUI

// XOR-swizzled LDS index (8-element chunks) to avoid padding
__device__ __forceinline__ int swz(int row, int k) {
  return ((((k >> 3) ^ (row & 15)) << 3) | (k & 7));
}

// ---------------- weight prep: combine + convert + transpose to [col][k] bf16 ----------------
__global__ void prep_weights(const float* __restrict__ W1l, const float* __restrict__ W1r,
                             const float* __restrict__ W2l, const float* __restrict__ W2r,
                             const float* __restrict__ b1, const float* __restrict__ b2,
                             __bf16* __restrict__ WT, float* __restrict__ bc) {
  int b = blockIdx.x, tid = threadIdx.x;
  if (b < 9) {
    const float* Wa; const float* Wb = nullptr;
    switch (b) {
      case 0: Wa = W1r + 1 * 16384; Wb = W1r + 3 * 16384; break;  // WTcu
      case 1: Wa = W1l + 3 * 16384; break;                        // W1l[3]
      case 2: Wa = W1l + 2 * 16384; break;                        // W1l[2]
      case 3: Wa = W1r + 2 * 16384; Wb = W1r + 4 * 16384; break;  // WTci
      case 4: Wa = W1l + 0 * 16384; break;                        // W1l[0]
      case 5: Wa = W1l + 5 * 16384; break;                        // W1l[5]
      case 6: Wa = W2r + 0 * 16384; Wb = W2r + 5 * 16384; break;  // WTcg
      case 7: Wa = W2l + 0 * 16384; break;                        // W2l[0]
      default: Wa = W2l + 5 * 16384; break;                       // W2l[5]
    }
    __bf16* dst = WT + b * 16384;
    for (int idx = tid; idx < 16384; idx += 256) {
      int k = idx >> 7, c = idx & 127;
      float v = Wa[idx];
      if (Wb) v += Wb[idx];
      dst[c * 128 + k] = (__bf16)v;
    }
  } else {
    if (tid < 128) {
      bc[tid]       = b1[128 + tid]     + b1[3 * 128 + tid];  // user
      bc[128 + tid] = b1[2 * 128 + tid] + b1[4 * 128 + tid];  // item
      bc[256 + tid] = b1[tid]           + b1[5 * 128 + tid];  // group L1
      bc[384 + tid] = b2[tid]           + b2[5 * 128 + tid];  // group L2
    }
  }
}

// pred_W [128, NI] fp32 -> predWT [NI, 128] bf16 (tiled LDS transpose)
__global__ void transpose_predw(const float* __restrict__ pw, __bf16* __restrict__ pwt) {
  __shared__ float t[64][65];
  int i0 = blockIdx.x * 64, k0 = blockIdx.y * 64;
  int tid = threadIdx.x;
  for (int idx = tid; idx < 64 * 16; idx += 256) {
    int kk = idx >> 4, c4 = (idx & 15) << 2;
    int ib = i0 + c4;
    float x0 = 0.f, x1 = 0.f, x2 = 0.f, x3 = 0.f;
    const float* src = pw + (size_t)(k0 + kk) * NI + ib;
    if (ib + 3 < NI) {
      const float4 v = *(const float4*)src;
      x0 = v.x; x1 = v.y; x2 = v.z; x3 = v.w;
    } else {
      if (ib + 0 < NI) x0 = src[0];
      if (ib + 1 < NI) x1 = src[1];
      if (ib + 2 < NI) x2 = src[2];
      if (ib + 3 < NI) x3 = src[3];
    }
    t[kk][c4 + 0] = x0; t[kk][c4 + 1] = x1; t[kk][c4 + 2] = x2; t[kk][c4 + 3] = x3;
  }
  __syncthreads();
  for (int idx = tid; idx < 64 * 16; idx += 256) {
    int ii = idx >> 4, k4 = (idx & 15) << 2;
    int gi = i0 + ii;
    if (gi < NI) {
      bf16x4 o;
      o[0] = (__bf16)t[k4 + 0][ii]; o[1] = (__bf16)t[k4 + 1][ii];
      o[2] = (__bf16)t[k4 + 2][ii]; o[3] = (__bf16)t[k4 + 3][ii];
      *(bf16x4*)(pwt + (size_t)gi * 128 + k0 + k4) = o;
    }
  }
}

// ---------------- CSR build ----------------
__global__ void hist_kernel(const int* __restrict__ key, int E, int* __restrict__ cnt) {
  int i = blockIdx.x * blockDim.x + threadIdx.x;
  if (i < E) atomicAdd(&cnt[key[i]], 1);
}

// 4 blocks, block b scans its own count array -> offs (exclusive) and cur copy
__global__ __launch_bounds__(1024) void scan4(int* __restrict__ cnt_all,
                                              int* __restrict__ offs_all,
                                              int* __restrict__ cur_all) {
  int b = blockIdx.x;
  int n;
  int *cnt, *offs, *cur;
  if (b == 0)      { n = NG; cnt = cnt_all;               offs = offs_all;                       cur = cur_all; }
  else if (b == 1) { n = NG; cnt = cnt_all + NG;          offs = offs_all + (NG + 1);            cur = cur_all + NG; }
  else if (b == 2) { n = NU; cnt = cnt_all + 2 * NG;      offs = offs_all + 2 * (NG + 1);        cur = cur_all + 2 * NG; }
  else             { n = NI; cnt = cnt_all + 2 * NG + NU; offs = offs_all + 2 * (NG + 1) + NU + 1; cur = cur_all + 2 * NG + NU; }

  __shared__ int wsum[16];
  __shared__ int carry_s;
  int tid = threadIdx.x, lane = tid & 63, wid = tid >> 6;
  if (tid == 0) carry_s = 0;
  __syncthreads();
  for (int base = 0; base < n; base += 1024) {
    int i = base + tid;
    int x = (i < n) ? cnt[i] : 0;
    int v = x;
#pragma unroll
    for (int d = 1; d < 64; d <<= 1) {
      int t = __shfl_up(v, d, 64);
      if (lane >= d) v += t;
    }
    if (lane == 63) wsum[wid] = v;
    __syncthreads();
    int wpre = 0;
    for (int w = 0; w < wid; ++w) wpre += wsum[w];
    int excl = carry_s + wpre + (v - x);
    if (i < n) { offs[i] = excl; cur[i] = excl; }
    int tot = 0;
    if (tid == 0) for (int w = 0; w < 16; ++w) tot += wsum[w];
    __syncthreads();
    if (tid == 0) carry_s += tot;
  }
  __syncthreads();
  if (threadIdx.x == 0) offs[n] = carry_s;
}

__global__ void fill_kernel(const int* __restrict__ payload, const int* __restrict__ key,
                            int E, int* __restrict__ cur, int* __restrict__ eidx) {
  int i = blockIdx.x * blockDim.x + threadIdx.x;
  if (i < E) {
    int pos = atomicAdd(&cur[key[i]], 1);
    eidx[pos] = payload[i];
  }
}

// ---------------- gather-based segment mean ----------------
__global__ void seg_mean(const float* __restrict__ feat, const int* __restrict__ offs,
                         const int* __restrict__ eidx, float* __restrict__ out) {
  int node = blockIdx.x;
  int col = threadIdx.x;  // 128 threads
  int s = offs[node], e = offs[node + 1];
  float acc = 0.f;
  for (int j = s; j < e; ++j) {
    int src = eidx[j];
    acc += feat[(size_t)src * 128 + col];
  }
  float inv = (e > s) ? (1.f / (float)(e - s)) : 0.f;
  out[(size_t)node * 128 + col] = acc * inv;
}

// ---------------- fused multi-term GEMM: C = act(sum_t A_t @ B_t + bias) ----------------
// A_t: [N,128] fp32 row-major.  B_t: [NC,128] bf16, B_t[col*128+k] == W[k][col].
// C: [N, NC] fp32.  Tile 128x128, 256 threads (4 waves, each a 64x64 quadrant).
__global__ __launch_bounds__(256)
void gemm_fused(const float* __restrict__ A0, const __bf16* __restrict__ B0,
                const float* __restrict__ A1, const __bf16* __restrict__ B1,
                const float* __restrict__ A2, const __bf16* __restrict__ B2,
                const float* __restrict__ bias, float* __restrict__ C,
                int N, int NC, int nterms, int relu) {
  __shared__ __bf16 sA[128 * 128];
  __shared__ __bf16 sB[128 * 128];
  int tid = threadIdx.x;
  int rowbase = blockIdx.x * 128, colbase = blockIdx.y * 128;
  int wid = tid >> 6, lane = tid & 63;
  int qrow = (wid >> 1) << 6, qcol = (wid & 1) << 6;
  int lrow = lane & 15, quad = lane >> 4;

  f32x4 acc[4][4];
#pragma unroll
  for (int mi = 0; mi < 4; ++mi)
#pragma unroll
    for (int ni = 0; ni < 4; ++ni) acc[mi][ni] = (f32x4){0.f, 0.f, 0.f, 0.f};

  const float* As[3] = {A0, A1, A2};
  const __bf16* Bs[3] = {B0, B1, B2};

  for (int t = 0; t < nterms; ++t) {
    __syncthreads();
    const float* A = As[t];
    for (int idx = tid; idx < 4096; idx += 256) {
      int row = idx >> 5, kc = (idx & 31) << 2;
      int grow = rowbase + row;
      float x0 = 0.f, x1 = 0.f, x2 = 0.f, x3 = 0.f;
      if (grow < N) {
        const float4 v = *(const float4*)(A + (size_t)grow * 128 + kc);
        x0 = v.x; x1 = v.y; x2 = v.z; x3 = v.w;
      }
      __bf16* p = &sA[row * 128 + swz(row, kc)];
      p[0] = (__bf16)x0; p[1] = (__bf16)x1; p[2] = (__bf16)x2; p[3] = (__bf16)x3;
    }
    const __bf16* B = Bs[t];
    for (int idx = tid; idx < 2048; idx += 256) {
      int n = idx >> 4, c8 = (idx & 15) << 3;
      int gcol = colbase + n;
      bf16x8 v;
      if (gcol < NC) v = *(const bf16x8*)(B + (size_t)gcol * 128 + c8);
      else
        for (int j = 0; j < 8; ++j) v[j] = (__bf16)0.f;
      *(bf16x8*)&sB[n * 128 + swz(n, c8)] = v;
    }
    __syncthreads();
#pragma unroll
    for (int kb = 0; kb < 4; ++kb) {
      int k0 = kb * 32 + quad * 8;
      bf16x8 af[4], bfr[4];
#pragma unroll
      for (int mi = 0; mi < 4; ++mi) {
        int r = qrow + mi * 16 + lrow;
        af[mi] = *(const bf16x8*)&sA[r * 128 + swz(r, k0)];
      }
#pragma unroll
      for (int ni = 0; ni < 4; ++ni) {
        int r = qcol + ni * 16 + lrow;
        bfr[ni] = *(const bf16x8*)&sB[r * 128 + swz(r, k0)];
      }
#pragma unroll
      for (int mi = 0; mi < 4; ++mi)
#pragma unroll
        for (int ni = 0; ni < 4; ++ni)
          acc[mi][ni] = __builtin_amdgcn_mfma_f32_16x16x32_bf16(af[mi], bfr[ni], acc[mi][ni], 0, 0, 0);
    }
  }

#pragma unroll
  for (int mi = 0; mi < 4; ++mi) {
#pragma unroll
    for (int ni = 0; ni < 4; ++ni) {
      int col = colbase + qcol + ni * 16 + lrow;
      if (col < NC) {
        float bv = bias[col];
#pragma unroll
        for (int r = 0; r < 4; ++r) {
          int row = rowbase + qrow + mi * 16 + quad * 4 + r;
          if (row < N) {
            float v = acc[mi][ni][r] + bv;
            if (relu) v = fmaxf(v, 0.f);
            C[(size_t)row * NC + col] = v;
          }
        }
      }
    }
  }
}

// ---------------- launch ----------------
extern "C" void kernel_launch(void* const* d_in, const int* in_sizes, int n_in,
                              void* d_out, int out_size, void* d_ws, size_t ws_size,
                              hipStream_t stream) {
  const float* emb_user = (const float*)d_in[4];
  const float* emb_item = (const float*)d_in[5];
  const float* W1l = (const float*)d_in[6];
  const float* W1r = (const float*)d_in[7];
  const float* b1  = (const float*)d_in[8];
  const float* W2l = (const float*)d_in[9];
  const float* W2r = (const float*)d_in[10];
  const float* b2  = (const float*)d_in[11];
  const float* predW = (const float*)d_in[12];
  const float* predb = (const float*)d_in[13];
  const int* ug_src = (const int*)d_in[14];
  const int* ug_dst = (const int*)d_in[15];
  const int* ui_src = (const int*)d_in[16];
  const int* ui_dst = (const int*)d_in[17];
  const int* gi_src = (const int*)d_in[18];
  const int* gi_dst = (const int*)d_in[19];

  char* ws = (char*)d_ws;
  float* aggU  = (float*)(ws + B_AGGU);
  float* aggI  = (float*)(ws + B_AGGI);
  float* aggG1 = (float*)(ws + B_AGGG1);
  float* aggG2 = (float*)(ws + B_AGGG2);
  float* aggG3 = (float*)(ws + B_AGGG3);
  float* bc    = (float*)(ws + B_BC);
  __bf16* predWT = (__bf16*)(ws + B_PWT);
  __bf16* WT     = (__bf16*)(ws + B_WT);
  int* cnt  = (int*)(ws + B_CNT);
  int* offs = (int*)(ws + B_OFFS);
  int* cur  = (int*)(ws + B_CUR);
  int* eidx = (int*)(ws + B_EIDX);

  int* cnt_ug  = cnt;
  int* cnt_gi  = cnt + NG;
  int* cnt_uiu = cnt + 2 * NG;
  int* cnt_uii = cnt + 2 * NG + NU;
  int* offs_ug  = offs;
  int* offs_gi  = offs + (NG + 1);
  int* offs_uiu = offs + 2 * (NG + 1);
  int* offs_uii = offs + 2 * (NG + 1) + (NU + 1);
  int* cur_ug  = cur;
  int* cur_gi  = cur + NG;
  int* cur_uiu = cur + 2 * NG;
  int* cur_uii = cur + 2 * NG + NU;
  int* e_ug  = eidx;
  int* e_gi  = eidx + EUG;
  int* e_uiu = eidx + EUG + EGI;
  int* e_uii = eidx + EUG + EGI + EUI;

  hipMemsetAsync(cnt, 0, 130000 * sizeof(int), stream);

  prep_weights<<<10, 256, 0, stream>>>(W1l, W1r, W2l, W2r, b1, b2, WT, bc);
  transpose_predw<<<dim3((NI + 63) / 64, 2), 256, 0, stream>>>(predW, predWT);

  hist_kernel<<<(EUG + 255) / 256, 256, 0, stream>>>(ug_dst, EUG, cnt_ug);
  hist_kernel<<<(EGI + 255) / 256, 256, 0, stream>>>(gi_src, EGI, cnt_gi);
  hist_kernel<<<(EUI + 255) / 256, 256, 0, stream>>>(ui_src, EUI, cnt_uiu);
  hist_kernel<<<(EUI + 255) / 256, 256, 0, stream>>>(ui_dst, EUI, cnt_uii);

  scan4<<<4, 1024, 0, stream>>>(cnt, offs, cur);

  // (payload, key): ug by group stores users; gi by group stores items;
  // ui by user stores items; ui by item stores users.
  fill_kernel<<<(EUG + 255) / 256, 256, 0, stream>>>(ug_src, ug_dst, EUG, cur_ug, e_ug);
  fill_kernel<<<(EGI + 255) / 256, 256, 0, stream>>>(gi_dst, gi_src, EGI, cur_gi, e_gi);
  fill_kernel<<<(EUI + 255) / 256, 256, 0, stream>>>(ui_dst, ui_src, EUI, cur_uiu, e_uiu);
  fill_kernel<<<(EUI + 255) / 256, 256, 0, stream>>>(ui_src, ui_dst, EUI, cur_uii, e_uii);

  // layer-1 aggregations (hg = 0 so g->u and g->i are skipped entirely)
  seg_mean<<<NU, 128, 0, stream>>>(emb_item, offs_uiu, e_uiu, aggU);   // i->u
  seg_mean<<<NI, 128, 0, stream>>>(emb_user, offs_uii, e_uii, aggI);   // u->i
  seg_mean<<<NG, 128, 0, stream>>>(emb_user, offs_ug, e_ug, aggG1);    // u->g
  seg_mean<<<NG, 128, 0, stream>>>(emb_item, offs_gi, e_gi, aggG2);    // i->g

  // layer-1 GEMMs (in-place outputs)
  gemm_fused<<<dim3((NU + 127) / 128, 1), 256, 0, stream>>>(
      emb_user, WT + 0 * 16384, aggU, WT + 1 * 16384, nullptr, nullptr,
      bc + 0, aggU, NU, 128, 2, 1);  // hu1
  gemm_fused<<<dim3((NI + 127) / 128, 1), 256, 0, stream>>>(
      aggI, WT + 2 * 16384, emb_item, WT + 3 * 16384, nullptr, nullptr,
      bc + 128, aggI, NI, 128, 2, 1);  // hi1
  gemm_fused<<<dim3((NG + 127) / 128, 1), 256, 0, stream>>>(
      aggG1, WT + 4 * 16384, aggG2, WT + 5 * 16384, nullptr, nullptr,
      bc + 256, aggG1, NG, 128, 2, 1);  // hg1

  // layer-2 aggregations (only group side is needed)
  seg_mean<<<NG, 128, 0, stream>>>(aggU, offs_ug, e_ug, aggG2);  // u->g (hu1)
  seg_mean<<<NG, 128, 0, stream>>>(aggI, offs_gi, e_gi, aggG3);  // i->g (hi1)

  // layer-2 group GEMM -> rep (in-place into aggG2)
  gemm_fused<<<dim3((NG + 127) / 128, 1), 256, 0, stream>>>(
      aggG2, WT + 7 * 16384, aggG1, WT + 6 * 16384, aggG3, WT + 8 * 16384,
      bc + 384, aggG2, NG, 128, 3, 1);

  // final: out = rep @ pred_W + pred_b   [NG, NI]
  gemm_fused<<<dim3((NG + 127) / 128, (NI + 127) / 128), 256, 0, stream>>>(
      aggG2, predWT, nullptr, nullptr, nullptr, nullptr,
      predb, (float*)d_out, NG, NI, 1, 0);
}

// Round 2
// 1055.313 us; speedup vs baseline: 1.3519x; 1.3519x over previous
//
#include <hip/hip_runtime.h>

typedef __bf16 bf16x8 __attribute__((ext_vector_type(8)));
typedef __bf16 bf16x4 __attribute__((ext_vector_type(4)));
typedef __bf16 bf16x2 __attribute__((ext_vector_type(2)));
typedef float  f32x4  __attribute__((ext_vector_type(4)));

#define NG 5000
#define NU 100000
#define NI 20000
#define H  128
#define EUG 300000
#define EUI 600000
#define EGI 200000
#define ETOT (EUG + EGI + EUI + EUI)   // 1,700,000
#define NN  (2 * NG + NU + NI)         // 130,000 concatenated nodes

// ---------------- workspace layout (bytes) ----------------
#define B_EMBU  0UL            // NU*H bf16 = 25,600,000
#define B_EMBI  25600000UL     // NI*H bf16 =  5,120,000
#define B_AGGU  30720000UL     // NU*H bf16 = 25,600,000   (i->u mean, then hu1 in-place)
#define B_AGGI  56320000UL     // NI*H bf16 =  5,120,000   (u->i mean, then hi1 in-place)
#define B_AGGG1 61440000UL     // NG*H bf16 =  1,280,000   (u->g mean L1, then hg1? no: hg1->B_HG1)
#define B_AGGG2 62720000UL     // NG*H bf16 =  1,280,000   (i->g mean L1)
#define B_HG1   64000000UL     // NG*H bf16
#define B_GU    65280000UL     // NG*H bf16 (L2 u->g of hu1)
#define B_GI    66560000UL     // NG*H bf16 (L2 i->g of hi1)
#define B_REP   67840000UL     // NG*H bf16 (relu(og2))
#define B_BC    69120000UL     // 4*128 f32 = 2048
#define B_PWT   69122048UL     // NI*H bf16 = 5,120,000
#define B_WT    74242048UL     // 9*16384 bf16 = 294,912
#define B_CNT   74536960UL     // NN int = 520,000
#define B_OFFS  75056960UL     // NN+1 int (+pad) = 520,016
#define B_CUR   75576976UL     // NN int = 520,000
#define B_EIDX  76096976UL     // ETOT int = 6,800,000  -> end 82,896,976

// chunksum/chunkbase (64 ints each) overlap B_AGGU: only live during scan,
// which completes before any seg_mean writes aggU. Stream-serialized => safe.

// concatenated node-segment bases (in NN space):
//   ug groups: 0 .. NG      | gi groups: NG .. 2NG
//   ui users : 2NG .. 2NG+NU | ui items: 2NG+NU .. NN

#define SCAN_CHUNK 2048
#define NCHUNK 64   // 64*2048 = 131072 >= NN

// XOR-swizzled LDS index (8-elem bf16 chunks)
__device__ __forceinline__ int swz(int row, int k) {
  return ((((k >> 3) ^ (row & 15)) << 3) | (k & 7));
}
// fp32 epilogue swizzle: flip bank-half by row quad -> max 2-way conflict (free)
__device__ __forceinline__ int cswz(int row, int col) {
  return col ^ (((row >> 2) & 1) << 4);
}

// ---------------- weight prep ----------------
__global__ void prep_weights(const float* __restrict__ W1l, const float* __restrict__ W1r,
                             const float* __restrict__ W2l, const float* __restrict__ W2r,
                             const float* __restrict__ b1, const float* __restrict__ b2,
                             __bf16* __restrict__ WT, float* __restrict__ bc) {
  int b = blockIdx.x, tid = threadIdx.x;
  if (b < 9) {
    const float* Wa; const float* Wb = nullptr;
    switch (b) {
      case 0: Wa = W1r + 1 * 16384; Wb = W1r + 3 * 16384; break;  // hu1: emb term
      case 1: Wa = W1l + 3 * 16384; break;                        // hu1: agg term
      case 2: Wa = W1l + 2 * 16384; break;                        // hi1: agg term
      case 3: Wa = W1r + 2 * 16384; Wb = W1r + 4 * 16384; break;  // hi1: emb term
      case 4: Wa = W1l + 0 * 16384; break;                        // hg1: u->g
      case 5: Wa = W1l + 5 * 16384; break;                        // hg1: i->g
      case 6: Wa = W2r + 0 * 16384; Wb = W2r + 5 * 16384; break;  // og2: hg1 term
      case 7: Wa = W2l + 0 * 16384; break;                        // og2: gU term
      default: Wa = W2l + 5 * 16384; break;                       // og2: gI term
    }
    __bf16* dst = WT + b * 16384;
    for (int idx = tid; idx < 16384; idx += 256) {
      int k = idx >> 7, c = idx & 127;
      float v = Wa[idx];
      if (Wb) v += Wb[idx];
      dst[c * 128 + k] = (__bf16)v;
    }
  } else {
    if (tid < 128) {
      bc[tid]       = b1[128 + tid]     + b1[3 * 128 + tid];  // user
      bc[128 + tid] = b1[2 * 128 + tid] + b1[4 * 128 + tid];  // item
      bc[256 + tid] = b1[tid]           + b1[5 * 128 + tid];  // group L1
      bc[384 + tid] = b2[tid]           + b2[5 * 128 + tid];  // group L2
    }
  }
}

// pred_W [128, NI] fp32 -> predWT [NI, 128] bf16
__global__ void transpose_predw(const float* __restrict__ pw, __bf16* __restrict__ pwt) {
  __shared__ float t[64][65];
  int i0 = blockIdx.x * 64, k0 = blockIdx.y * 64;
  int tid = threadIdx.x;
  for (int idx = tid; idx < 64 * 16; idx += 256) {
    int kk = idx >> 4, c4 = (idx & 15) << 2;
    int ib = i0 + c4;
    float x0 = 0.f, x1 = 0.f, x2 = 0.f, x3 = 0.f;
    const float* src = pw + (size_t)(k0 + kk) * NI + ib;
    if (ib + 3 < NI) {
      const float4 v = *(const float4*)src;
      x0 = v.x; x1 = v.y; x2 = v.z; x3 = v.w;
    } else {
      if (ib + 0 < NI) x0 = src[0];
      if (ib + 1 < NI) x1 = src[1];
      if (ib + 2 < NI) x2 = src[2];
      if (ib + 3 < NI) x3 = src[3];
    }
    t[kk][c4 + 0] = x0; t[kk][c4 + 1] = x1; t[kk][c4 + 2] = x2; t[kk][c4 + 3] = x3;
  }
  __syncthreads();
  for (int idx = tid; idx < 64 * 16; idx += 256) {
    int ii = idx >> 4, k4 = (idx & 15) << 2;
    int gi = i0 + ii;
    if (gi < NI) {
      bf16x4 o;
      o[0] = (__bf16)t[k4 + 0][ii]; o[1] = (__bf16)t[k4 + 1][ii];
      o[2] = (__bf16)t[k4 + 2][ii]; o[3] = (__bf16)t[k4 + 3][ii];
      *(bf16x4*)(pwt + (size_t)gi * 128 + k0 + k4) = o;
    }
  }
}

// fp32 -> bf16 feature convert (n4 float4s)
__global__ void cvt_bf16(const float* __restrict__ src, __bf16* __restrict__ dst, int n4) {
  int i = blockIdx.x * 256 + threadIdx.x;
  if (i < n4) {
    float4 v = ((const float4*)src)[i];
    bf16x4 o;
    o[0] = (__bf16)v.x; o[1] = (__bf16)v.y; o[2] = (__bf16)v.z; o[3] = (__bf16)v.w;
    ((bf16x4*)dst)[i] = o;
  }
}

// ---------------- CSR build (fused) ----------------
__global__ void hist_all(const int* __restrict__ ug_dst, const int* __restrict__ gi_src,
                         const int* __restrict__ ui_src, const int* __restrict__ ui_dst,
                         int* __restrict__ cnt) {
  int i = blockIdx.x * 256 + threadIdx.x;
  int key, base;
  if (i < EUG)                       { key = ug_dst[i];                   base = 0; }
  else if (i < EUG + EGI)            { key = gi_src[i - EUG];             base = NG; }
  else if (i < EUG + EGI + EUI)      { key = ui_src[i - EUG - EGI];       base = 2 * NG; }
  else if (i < ETOT)                 { key = ui_dst[i - EUG - EGI - EUI]; base = 2 * NG + NU; }
  else return;
  atomicAdd(&cnt[base + key], 1);
}

__global__ void scan_k1(const int* __restrict__ cnt, int* __restrict__ chunksum) {
  __shared__ int ws[4];
  int b = blockIdx.x, tid = threadIdx.x, lane = tid & 63, w = tid >> 6;
  int base = b * SCAN_CHUNK + tid * 8;
  int s = 0;
#pragma unroll
  for (int j = 0; j < 8; ++j) { int i = base + j; if (i < NN) s += cnt[i]; }
#pragma unroll
  for (int d = 1; d < 64; d <<= 1) s += __shfl_xor(s, d, 64);
  if (lane == 0) ws[w] = s;
  __syncthreads();
  if (tid == 0) chunksum[b] = ws[0] + ws[1] + ws[2] + ws[3];
}

__global__ void scan_k2(const int* __restrict__ chunksum, int* __restrict__ chunkbase) {
  int lane = threadIdx.x;  // 64 threads
  int v = chunksum[lane];
  int incl = v;
#pragma unroll
  for (int d = 1; d < 64; d <<= 1) { int t = __shfl_up(incl, d, 64); if (lane >= d) incl += t; }
  chunkbase[lane] = incl - v;
}

__global__ void scan_k3(const int* __restrict__ cnt, const int* __restrict__ chunkbase,
                        int* __restrict__ offs, int* __restrict__ cur) {
  __shared__ int ws[4];
  int b = blockIdx.x, tid = threadIdx.x, lane = tid & 63, w = tid >> 6;
  int base = b * SCAN_CHUNK + tid * 8;
  int x[8]; int s = 0;
#pragma unroll
  for (int j = 0; j < 8; ++j) { int i = base + j; x[j] = (i < NN) ? cnt[i] : 0; s += x[j]; }
  int incl = s;
#pragma unroll
  for (int d = 1; d < 64; d <<= 1) { int t = __shfl_up(incl, d, 64); if (lane >= d) incl += t; }
  if (lane == 63) ws[w] = incl;
  __syncthreads();
  int wpre = 0;
  for (int ww = 0; ww < w; ++ww) wpre += ws[ww];
  int excl = chunkbase[b] + wpre + incl - s;
#pragma unroll
  for (int j = 0; j < 8; ++j) {
    int i = base + j;
    if (i < NN) { offs[i] = excl; cur[i] = excl; }
    excl += x[j];
    if (i == NN - 1) offs[NN] = excl;
  }
}

__global__ void fill_all(const int* __restrict__ ug_src, const int* __restrict__ ug_dst,
                         const int* __restrict__ gi_src, const int* __restrict__ gi_dst,
                         const int* __restrict__ ui_src, const int* __restrict__ ui_dst,
                         int* __restrict__ cur, int* __restrict__ eidx) {
  int i = blockIdx.x * 256 + threadIdx.x;
  int key, base, payload;
  if (i < EUG)                  { key = ug_dst[i];       base = 0;            payload = ug_src[i]; }
  else if (i < EUG + EGI)       { int j = i - EUG;       key = gi_src[j]; base = NG;          payload = gi_dst[j]; }
  else if (i < EUG + EGI + EUI) { int j = i - EUG - EGI; key = ui_src[j]; base = 2 * NG;      payload = ui_dst[j]; }
  else if (i < ETOT)            { int j = i - EUG - EGI - EUI; key = ui_dst[j]; base = 2 * NG + NU; payload = ui_src[j]; }
  else return;
  int pos = atomicAdd(&cur[base + key], 1);
  eidx[pos] = payload;
}

// ---------------- gather-based segment mean (bf16 in/out, fp32 accum) ----------------
// one wave per node, 4 nodes/block; lane covers 2 cols (bf16x2)
__global__ __launch_bounds__(256)
void seg_mean_bf(const __bf16* __restrict__ feat, const int* __restrict__ offs,
                 const int* __restrict__ eidx, __bf16* __restrict__ out, int nnode) {
  int w = threadIdx.x >> 6, lane = threadIdx.x & 63;
  int node = blockIdx.x * 4 + w;
  if (node >= nnode) return;
  int s = offs[node], e = offs[node + 1];
  float a0 = 0.f, a1 = 0.f;
  int j = s;
  for (; j + 4 <= e; j += 4) {
    int i0 = eidx[j], i1 = eidx[j + 1], i2 = eidx[j + 2], i3 = eidx[j + 3];
    bf16x2 v0 = *(const bf16x2*)(feat + (size_t)i0 * 128 + lane * 2);
    bf16x2 v1 = *(const bf16x2*)(feat + (size_t)i1 * 128 + lane * 2);
    bf16x2 v2 = *(const bf16x2*)(feat + (size_t)i2 * 128 + lane * 2);
    bf16x2 v3 = *(const bf16x2*)(feat + (size_t)i3 * 128 + lane * 2);
    a0 += (float)v0[0] + (float)v1[0] + (float)v2[0] + (float)v3[0];
    a1 += (float)v0[1] + (float)v1[1] + (float)v2[1] + (float)v3[1];
  }
  for (; j < e; ++j) {
    int i0 = eidx[j];
    bf16x2 v0 = *(const bf16x2*)(feat + (size_t)i0 * 128 + lane * 2);
    a0 += (float)v0[0]; a1 += (float)v0[1];
  }
  float inv = (e > s) ? (1.f / (float)(e - s)) : 0.f;
  bf16x2 o;
  o[0] = (__bf16)(a0 * inv); o[1] = (__bf16)(a1 * inv);
  *(bf16x2*)(out + (size_t)node * 128 + lane * 2) = o;
}

// ---------------- fused multi-term GEMM: C = act(sum_t A_t @ B_t + bias) ----------------
// A_t: [N,128] bf16 row-major. B_t: [NC,128] bf16 ([col][k]). Out fp32 (Cf) or bf16 (Cb).
__global__ __launch_bounds__(256)
void gemm_fused(const __bf16* __restrict__ A0, const __bf16* __restrict__ B0,
                const __bf16* __restrict__ A1, const __bf16* __restrict__ B1,
                const __bf16* __restrict__ A2, const __bf16* __restrict__ B2,
                const float* __restrict__ bias, float* __restrict__ Cf,
                __bf16* __restrict__ Cb, int N, int NC, int nterms, int relu) {
  __shared__ char smem_raw[128 * 128 * 4];   // 64 KB: sA+sB (bf16) union sC (fp32)
  __bf16* sA = (__bf16*)smem_raw;
  __bf16* sB = sA + 128 * 128;
  float* sC = (float*)smem_raw;
  int tid = threadIdx.x;
  int rowbase = blockIdx.x * 128, colbase = blockIdx.y * 128;
  int wid = tid >> 6, lane = tid & 63;
  int qrow = (wid >> 1) << 6, qcol = (wid & 1) << 6;
  int lrow = lane & 15, quad = lane >> 4;

  f32x4 acc[4][4];
#pragma unroll
  for (int mi = 0; mi < 4; ++mi)
#pragma unroll
    for (int ni = 0; ni < 4; ++ni) acc[mi][ni] = (f32x4){0.f, 0.f, 0.f, 0.f};

  const __bf16* As[3] = {A0, A1, A2};
  const __bf16* Bs[3] = {B0, B1, B2};

  for (int t = 0; t < nterms; ++t) {
    __syncthreads();
    const __bf16* A = As[t];
    for (int idx = tid; idx < 2048; idx += 256) {
      int row = idx >> 4, c8 = (idx & 15) << 3;
      int grow = rowbase + row;
      bf16x8 v;
      if (grow < N) v = *(const bf16x8*)(A + (size_t)grow * 128 + c8);
      else { for (int u = 0; u < 8; ++u) v[u] = (__bf16)0.f; }
      *(bf16x8*)&sA[row * 128 + swz(row, c8)] = v;
    }
    const __bf16* B = Bs[t];
    for (int idx = tid; idx < 2048; idx += 256) {
      int n = idx >> 4, c8 = (idx & 15) << 3;
      int gcol = colbase + n;
      bf16x8 v;
      if (gcol < NC) v = *(const bf16x8*)(B + (size_t)gcol * 128 + c8);
      else { for (int u = 0; u < 8; ++u) v[u] = (__bf16)0.f; }
      *(bf16x8*)&sB[n * 128 + swz(n, c8)] = v;
    }
    __syncthreads();
#pragma unroll
    for (int kb = 0; kb < 4; ++kb) {
      int k0 = kb * 32 + quad * 8;
      bf16x8 af[4], bfr[4];
#pragma unroll
      for (int mi = 0; mi < 4; ++mi) {
        int r = qrow + mi * 16 + lrow;
        af[mi] = *(const bf16x8*)&sA[r * 128 + swz(r, k0)];
      }
#pragma unroll
      for (int ni = 0; ni < 4; ++ni) {
        int r = qcol + ni * 16 + lrow;
        bfr[ni] = *(const bf16x8*)&sB[r * 128 + swz(r, k0)];
      }
#pragma unroll
      for (int mi = 0; mi < 4; ++mi)
#pragma unroll
        for (int ni = 0; ni < 4; ++ni)
          acc[mi][ni] = __builtin_amdgcn_mfma_f32_16x16x32_bf16(af[mi], bfr[ni], acc[mi][ni], 0, 0, 0);
    }
  }

  // epilogue: acc -> LDS (fp32, swizzled) -> coalesced global stores
  __syncthreads();
#pragma unroll
  for (int mi = 0; mi < 4; ++mi) {
#pragma unroll
    for (int ni = 0; ni < 4; ++ni) {
      int col = qcol + ni * 16 + lrow;
#pragma unroll
      for (int r = 0; r < 4; ++r) {
        int row = qrow + mi * 16 + quad * 4 + r;
        sC[row * 128 + cswz(row, col)] = acc[mi][ni][r];
      }
    }
  }
  __syncthreads();
  for (int idx = tid; idx < 4096; idx += 256) {
    int row = idx >> 5, c4 = (idx & 31) << 2;
    int grow = rowbase + row, gcol = colbase + c4;
    if (grow >= N) continue;
    f32x4 v = *(const f32x4*)&sC[row * 128 + cswz(row, c4)];
    if (gcol + 3 < NC) {
      f32x4 bv = *(const f32x4*)&bias[gcol];
      v += bv;
      if (relu) {
#pragma unroll
        for (int u = 0; u < 4; ++u) v[u] = fmaxf(v[u], 0.f);
      }
      if (Cb) {
        bf16x4 o;
        o[0] = (__bf16)v[0]; o[1] = (__bf16)v[1]; o[2] = (__bf16)v[2]; o[3] = (__bf16)v[3];
        *(bf16x4*)(Cb + (size_t)grow * NC + gcol) = o;
      } else {
        *(f32x4*)(Cf + (size_t)grow * NC + gcol) = v;
      }
    } else {
#pragma unroll
      for (int u = 0; u < 4; ++u) {
        if (gcol + u < NC) {
          float x = v[u] + bias[gcol + u];
          if (relu) x = fmaxf(x, 0.f);
          if (Cb) Cb[(size_t)grow * NC + gcol + u] = (__bf16)x;
          else    Cf[(size_t)grow * NC + gcol + u] = x;
        }
      }
    }
  }
}

// ---------------- launch ----------------
extern "C" void kernel_launch(void* const* d_in, const int* in_sizes, int n_in,
                              void* d_out, int out_size, void* d_ws, size_t ws_size,
                              hipStream_t stream) {
  const float* emb_user = (const float*)d_in[4];
  const float* emb_item = (const float*)d_in[5];
  const float* W1l = (const float*)d_in[6];
  const float* W1r = (const float*)d_in[7];
  const float* b1  = (const float*)d_in[8];
  const float* W2l = (const float*)d_in[9];
  const float* W2r = (const float*)d_in[10];
  const float* b2  = (const float*)d_in[11];
  const float* predW = (const float*)d_in[12];
  const float* predb = (const float*)d_in[13];
  const int* ug_src = (const int*)d_in[14];
  const int* ug_dst = (const int*)d_in[15];
  const int* ui_src = (const int*)d_in[16];
  const int* ui_dst = (const int*)d_in[17];
  const int* gi_src = (const int*)d_in[18];
  const int* gi_dst = (const int*)d_in[19];

  char* ws = (char*)d_ws;
  __bf16* embU = (__bf16*)(ws + B_EMBU);
  __bf16* embI = (__bf16*)(ws + B_EMBI);
  __bf16* aggU = (__bf16*)(ws + B_AGGU);
  __bf16* aggI = (__bf16*)(ws + B_AGGI);
  __bf16* aggG1 = (__bf16*)(ws + B_AGGG1);
  __bf16* aggG2 = (__bf16*)(ws + B_AGGG2);
  __bf16* hg1 = (__bf16*)(ws + B_HG1);
  __bf16* gU  = (__bf16*)(ws + B_GU);
  __bf16* gI  = (__bf16*)(ws + B_GI);
  __bf16* rep = (__bf16*)(ws + B_REP);
  float* bc    = (float*)(ws + B_BC);
  __bf16* predWT = (__bf16*)(ws + B_PWT);
  __bf16* WT     = (__bf16*)(ws + B_WT);
  int* cnt  = (int*)(ws + B_CNT);
  int* offs = (int*)(ws + B_OFFS);
  int* cur  = (int*)(ws + B_CUR);
  int* eidx = (int*)(ws + B_EIDX);
  // scan scratch overlaps aggU (dead until seg_mean phase)
  int* chunksum  = (int*)(ws + B_AGGU);
  int* chunkbase = chunksum + NCHUNK;

  const int* offs_ug  = offs;                 // groups via ug
  const int* offs_gi  = offs + NG;            // groups via gi
  const int* offs_uiu = offs + 2 * NG;        // users via ui
  const int* offs_uii = offs + 2 * NG + NU;   // items via ui

  hipMemsetAsync(cnt, 0, NN * sizeof(int), stream);

  prep_weights<<<10, 256, 0, stream>>>(W1l, W1r, W2l, W2r, b1, b2, WT, bc);
  transpose_predw<<<dim3((NI + 63) / 64, 2), 256, 0, stream>>>(predW, predWT);
  cvt_bf16<<<(NU * 32 + 255) / 256, 256, 0, stream>>>(emb_user, embU, NU * 32);
  cvt_bf16<<<(NI * 32 + 255) / 256, 256, 0, stream>>>(emb_item, embI, NI * 32);

  hist_all<<<(ETOT + 255) / 256, 256, 0, stream>>>(ug_dst, gi_src, ui_src, ui_dst, cnt);
  scan_k1<<<NCHUNK, 256, 0, stream>>>(cnt, chunksum);
  scan_k2<<<1, 64, 0, stream>>>(chunksum, chunkbase);
  scan_k3<<<NCHUNK, 256, 0, stream>>>(cnt, chunkbase, offs, cur);
  fill_all<<<(ETOT + 255) / 256, 256, 0, stream>>>(ug_src, ug_dst, gi_src, gi_dst,
                                                   ui_src, ui_dst, cur, eidx);

  // layer-1 aggregations (hg = 0 so g->u / g->i are skipped)
  seg_mean_bf<<<(NU + 3) / 4, 256, 0, stream>>>(embI, offs_uiu, eidx, aggU, NU);  // i->u
  seg_mean_bf<<<(NI + 3) / 4, 256, 0, stream>>>(embU, offs_uii, eidx, aggI, NI);  // u->i
  seg_mean_bf<<<(NG + 3) / 4, 256, 0, stream>>>(embU, offs_ug, eidx, aggG1, NG);  // u->g
  seg_mean_bf<<<(NG + 3) / 4, 256, 0, stream>>>(embI, offs_gi, eidx, aggG2, NG);  // i->g

  // layer-1 GEMMs (bf16 out, relu); hu1/hi1 in-place
  gemm_fused<<<dim3((NU + 127) / 128, 1), 256, 0, stream>>>(
      embU, WT + 0 * 16384, aggU, WT + 1 * 16384, nullptr, nullptr,
      bc + 0, nullptr, aggU, NU, 128, 2, 1);  // hu1
  gemm_fused<<<dim3((NI + 127) / 128, 1), 256, 0, stream>>>(
      aggI, WT + 2 * 16384, embI, WT + 3 * 16384, nullptr, nullptr,
      bc + 128, nullptr, aggI, NI, 128, 2, 1);  // hi1
  gemm_fused<<<dim3((NG + 127) / 128, 1), 256, 0, stream>>>(
      aggG1, WT + 4 * 16384, aggG2, WT + 5 * 16384, nullptr, nullptr,
      bc + 256, nullptr, hg1, NG, 128, 2, 1);  // hg1

  // layer-2 aggregations (group side only)
  seg_mean_bf<<<(NG + 3) / 4, 256, 0, stream>>>(aggU, offs_ug, eidx, gU, NG);  // u->g (hu1)
  seg_mean_bf<<<(NG + 3) / 4, 256, 0, stream>>>(aggI, offs_gi, eidx, gI, NG);  // i->g (hi1)

  // layer-2 group GEMM -> rep (bf16, relu)
  gemm_fused<<<dim3((NG + 127) / 128, 1), 256, 0, stream>>>(
      gU, WT + 7 * 16384, hg1, WT + 6 * 16384, gI, WT + 8 * 16384,
      bc + 384, nullptr, rep, NG, 128, 3, 1);

  // final: out = rep @ pred_W + pred_b   [NG, NI] fp32
  gemm_fused<<<dim3((NG + 127) / 128, (NI + 127) / 128), 256, 0, stream>>>(
      rep, predWT, nullptr, nullptr, nullptr, nullptr,
      predb, (float*)d_out, nullptr, NG, NI, 1, 0);
}